// Round 1
// baseline (470.301 us; speedup 1.0000x reference)
//
#include <hip/hip_runtime.h>

#define B 32
#define T 2048
#define H 1024

// ---------------------------------------------------------------------------
// K1: v[b,h] = sum_o hidden[b,o] * W[o,h]   (i.e. v[b] = hidden[b] @ W)
// grid (H/256, B), 256 threads. hidden row staged in LDS; W reads coalesced.
// W is only 4 MB -> L2/L3 serve the 32x re-reads across b.
// ---------------------------------------------------------------------------
__global__ __launch_bounds__(256) void compute_v_kernel(
    const float* __restrict__ hidden, const float* __restrict__ W,
    float* __restrict__ v) {
  __shared__ float sh[H];
  const int b = blockIdx.y;
  const int h = blockIdx.x * 256 + threadIdx.x;
  for (int i = threadIdx.x; i < H; i += 256) sh[i] = hidden[b * H + i];
  __syncthreads();
  float acc = 0.f;
#pragma unroll 8
  for (int o = 0; o < H; ++o) acc = fmaf(sh[o], W[o * H + h], acc);
  v[b * H + h] = acc;
}

// ---------------------------------------------------------------------------
// K2: score[b,t] = dot(enc[b,t,:], v[b,:])  -> written into out_attn (raw)
// grid (T/128, B) = 512 blocks, 256 threads = 4 waves.
// Each wave owns one t per iteration; lane reads 4 float4s (coalesced 4KB/row),
// v fragment preloaded in registers, 6-step shfl reduce.
// ---------------------------------------------------------------------------
__global__ __launch_bounds__(256) void scores_kernel(
    const float* __restrict__ enc, const float* __restrict__ v,
    float* __restrict__ score) {
  const int b = blockIdx.y;
  const int wave = threadIdx.x >> 6;
  const int lane = threadIdx.x & 63;
  const float4* v4 = (const float4*)(v + b * H);
  float4 vr[4];
#pragma unroll
  for (int j = 0; j < 4; ++j) vr[j] = v4[j * 64 + lane];
  const int t0 = blockIdx.x * 128;
  for (int it = 0; it < 32; ++it) {
    const int t = t0 + it * 4 + wave;
    const float4* e4 = (const float4*)(enc + ((size_t)b * T + t) * H);
    float acc = 0.f;
#pragma unroll
    for (int j = 0; j < 4; ++j) {
      float4 e = e4[j * 64 + lane];
      acc += e.x * vr[j].x + e.y * vr[j].y + e.z * vr[j].z + e.w * vr[j].w;
    }
#pragma unroll
    for (int off = 32; off; off >>= 1) acc += __shfl_down(acc, off, 64);
    if (lane == 0) score[b * T + t] = acc;
  }
}

// ---------------------------------------------------------------------------
// K3: softmax over T, in place on out_attn. grid B, 256 threads, 8 elems/thread.
// ---------------------------------------------------------------------------
__global__ __launch_bounds__(256) void softmax_kernel(float* __restrict__ score) {
  const int b = blockIdx.x;
  const int tid = threadIdx.x;
  const int wave = tid >> 6;
  const int lane = tid & 63;
  __shared__ float red[4];
  float* row = score + b * T;

  float x[8];
  float m = -1e30f;
#pragma unroll
  for (int j = 0; j < 8; ++j) {
    x[j] = row[j * 256 + tid];
    m = fmaxf(m, x[j]);
  }
#pragma unroll
  for (int off = 32; off; off >>= 1) m = fmaxf(m, __shfl_down(m, off, 64));
  if (lane == 0) red[wave] = m;
  __syncthreads();
  m = fmaxf(fmaxf(red[0], red[1]), fmaxf(red[2], red[3]));
  __syncthreads();

  float e[8];
  float s = 0.f;
#pragma unroll
  for (int j = 0; j < 8; ++j) {
    e[j] = __expf(x[j] - m);
    s += e[j];
  }
#pragma unroll
  for (int off = 32; off; off >>= 1) s += __shfl_down(s, off, 64);
  if (lane == 0) red[wave] = s;
  __syncthreads();
  const float inv = 1.f / (red[0] + red[1] + red[2] + red[3]);
#pragma unroll
  for (int j = 0; j < 8; ++j) row[j * 256 + tid] = e[j] * inv;
}

// ---------------------------------------------------------------------------
// K4: partial context over a 128-row t-chunk.
// grid (16, B) = 512 blocks, 256 threads; thread owns one float4 of H.
// partial[b, c, :] = sum_{t in chunk c} attn[b,t] * enc[b,t,:]
// ---------------------------------------------------------------------------
#define TCH 128
#define NCH (T / TCH)  // 16
__global__ __launch_bounds__(256) void context_partial_kernel(
    const float* __restrict__ enc, const float* __restrict__ attn,
    float* __restrict__ partial) {
  const int b = blockIdx.y;
  const int c = blockIdx.x;
  const int tid = threadIdx.x;
  __shared__ float wa[TCH];
  if (tid < TCH) wa[tid] = attn[b * T + c * TCH + tid];
  __syncthreads();
  float4 acc = {0.f, 0.f, 0.f, 0.f};
  const float4* base = (const float4*)(enc + ((size_t)b * T + c * TCH) * H);
  for (int t = 0; t < TCH; ++t) {
    const float w = wa[t];
    float4 e = base[(size_t)t * (H / 4) + tid];
    acc.x = fmaf(w, e.x, acc.x);
    acc.y = fmaf(w, e.y, acc.y);
    acc.z = fmaf(w, e.z, acc.z);
    acc.w = fmaf(w, e.w, acc.w);
  }
  ((float4*)(partial + ((size_t)b * NCH + c) * H))[tid] = acc;
}

// ---------------------------------------------------------------------------
// K5: context[b,:] = sum_c partial[b,c,:]. grid B, 256 threads.
// ---------------------------------------------------------------------------
__global__ __launch_bounds__(256) void context_reduce_kernel(
    const float* __restrict__ partial, float* __restrict__ ctx) {
  const int b = blockIdx.x;
  const int tid = threadIdx.x;
  float4 acc = {0.f, 0.f, 0.f, 0.f};
  const float4* p = (const float4*)(partial + (size_t)b * NCH * H);
#pragma unroll
  for (int c = 0; c < NCH; ++c) {
    float4 e = p[c * (H / 4) + tid];
    acc.x += e.x;
    acc.y += e.y;
    acc.z += e.z;
    acc.w += e.w;
  }
  ((float4*)(ctx + b * H))[tid] = acc;
}

extern "C" void kernel_launch(void* const* d_in, const int* in_sizes, int n_in,
                              void* d_out, int out_size, void* d_ws,
                              size_t ws_size, hipStream_t stream) {
  const float* hidden = (const float*)d_in[0];  // [B,H]
  const float* enc = (const float*)d_in[1];     // [B,T,H]
  const float* W = (const float*)d_in[2];       // [H,H]

  float* out = (float*)d_out;
  float* out_ctx = out;          // [B,H]
  float* out_attn = out + B * H; // [B,T]

  float* v = (float*)d_ws;            // B*H floats
  float* partial = v + B * H;         // B*NCH*H floats

  compute_v_kernel<<<dim3(H / 256, B), 256, 0, stream>>>(hidden, W, v);
  scores_kernel<<<dim3(T / 128, B), 256, 0, stream>>>(enc, v, out_attn);
  softmax_kernel<<<B, 256, 0, stream>>>(out_attn);
  context_partial_kernel<<<dim3(NCH, B), 256, 0, stream>>>(enc, out_attn, partial);
  context_reduce_kernel<<<B, 256, 0, stream>>>(partial, out_ctx);
}

// Round 3
// 424.485 us; speedup vs baseline: 1.1079x; 1.1079x over previous
//
#include <hip/hip_runtime.h>

#define B 32
#define T 2048
#define H 1024

// ---------------------------------------------------------------------------
// K1: v[b,h] = sum_o hidden[b,o] * W[o,h]   (v[b] = hidden[b] @ W)
// grid (H/64, B) = 512 blocks, 256 threads = 4 o-groups x 64 h-lanes.
// Each o-group (one wave) covers 256 o-values with 8 independent accumulators
// (8 loads in flight); LDS reduce across the 4 groups. W stays hot in L2.
// ---------------------------------------------------------------------------
__global__ __launch_bounds__(256) void compute_v_kernel(
    const float* __restrict__ hidden, const float* __restrict__ W,
    float* __restrict__ v) {
  const int b = blockIdx.y;
  const int og = threadIdx.x >> 6;   // 0..3 (== wave id)
  const int hl = threadIdx.x & 63;
  const int h = blockIdx.x * 64 + hl;
  __shared__ float sh[H];
  __shared__ float red[4][64];
  for (int i = threadIdx.x; i < H; i += 256) sh[i] = hidden[b * H + i];
  __syncthreads();
  float acc[8] = {0.f, 0.f, 0.f, 0.f, 0.f, 0.f, 0.f, 0.f};
  const int ob = og * 256;
  for (int oo = 0; oo < 256; oo += 8) {
#pragma unroll
    for (int k = 0; k < 8; ++k) {
      const int o = ob + oo + k;
      acc[k] = fmaf(sh[o], W[(size_t)o * H + h], acc[k]);
    }
  }
  float a = ((acc[0] + acc[1]) + (acc[2] + acc[3])) +
            ((acc[4] + acc[5]) + (acc[6] + acc[7]));
  red[og][hl] = a;
  __syncthreads();
  if (og == 0)
    v[b * H + h] = (red[0][hl] + red[1][hl]) + (red[2][hl] + red[3][hl]);
}

// ---------------------------------------------------------------------------
// K2: score[b,t] = dot(enc[b,t,:], v[b,:])  (raw scores -> out_attn region)
// grid (T/64, B) = 1024 blocks (4/CU, 16 waves/CU), 256 threads = 4 waves.
// Each wave owns 16 rows, processed 2 at a time: 8 float4 loads in flight,
// two independent shfl-reduce chains.
// ---------------------------------------------------------------------------
__global__ __launch_bounds__(256) void scores_kernel(
    const float* __restrict__ enc, const float* __restrict__ v,
    float* __restrict__ score) {
  const int b = blockIdx.y;
  const int wave = threadIdx.x >> 6;
  const int lane = threadIdx.x & 63;
  const float4* v4 = (const float4*)(v + b * H);
  float4 vr[4];
#pragma unroll
  for (int j = 0; j < 4; ++j) vr[j] = v4[j * 64 + lane];
  const int t0 = blockIdx.x * 64 + wave * 16;
  for (int it = 0; it < 16; it += 2) {
    const int ta = t0 + it, tb = t0 + it + 1;
    const float4* ea4 = (const float4*)(enc + ((size_t)b * T + ta) * H);
    const float4* eb4 = (const float4*)(enc + ((size_t)b * T + tb) * H);
    float4 ea[4], eb[4];
#pragma unroll
    for (int j = 0; j < 4; ++j) ea[j] = ea4[j * 64 + lane];
#pragma unroll
    for (int j = 0; j < 4; ++j) eb[j] = eb4[j * 64 + lane];
    float accA = 0.f, accB = 0.f;
#pragma unroll
    for (int j = 0; j < 4; ++j) {
      accA += ea[j].x * vr[j].x + ea[j].y * vr[j].y + ea[j].z * vr[j].z +
              ea[j].w * vr[j].w;
      accB += eb[j].x * vr[j].x + eb[j].y * vr[j].y + eb[j].z * vr[j].z +
              eb[j].w * vr[j].w;
    }
#pragma unroll
    for (int off = 32; off; off >>= 1) {
      accA += __shfl_down(accA, off, 64);
      accB += __shfl_down(accB, off, 64);
    }
    if (lane == 0) {
      score[b * T + ta] = accA;
      score[b * T + tb] = accB;
    }
  }
}

// ---------------------------------------------------------------------------
// K3: per-b softmax stats only: stats[b] = {max, 1/sum(exp(x-max))}.
// grid B, 256 threads, 8 elems/thread (reads 256 KB total).
// ---------------------------------------------------------------------------
__global__ __launch_bounds__(256) void softmax_stats_kernel(
    const float* __restrict__ score, float2* __restrict__ stats) {
  const int b = blockIdx.x;
  const int tid = threadIdx.x;
  const int wave = tid >> 6;
  const int lane = tid & 63;
  __shared__ float red[4];
  const float* row = score + b * T;

  float x[8];
  float m = -1e30f;
#pragma unroll
  for (int j = 0; j < 8; ++j) {
    x[j] = row[j * 256 + tid];
    m = fmaxf(m, x[j]);
  }
#pragma unroll
  for (int off = 32; off; off >>= 1) m = fmaxf(m, __shfl_down(m, off, 64));
  if (lane == 0) red[wave] = m;
  __syncthreads();
  m = fmaxf(fmaxf(red[0], red[1]), fmaxf(red[2], red[3]));
  __syncthreads();

  float s = 0.f;
#pragma unroll
  for (int j = 0; j < 8; ++j) s += __expf(x[j] - m);
#pragma unroll
  for (int off = 32; off; off >>= 1) s += __shfl_down(s, off, 64);
  if (lane == 0) red[wave] = s;
  __syncthreads();
  if (tid == 0) {
    const float total = (red[0] + red[1]) + (red[2] + red[3]);
    stats[b] = make_float2(m, 1.f / total);
  }
}

// ---------------------------------------------------------------------------
// K4: fused normalize + partial context over a 64-row t-chunk.
// grid (T/64, B) = 1024 blocks, 256 threads; thread owns one float4 of H.
// Reads raw scores, writes normalized weights back (no hazard: each block
// owns its 64-score chunk exclusively), accumulates partial[b,c,:] with 4
// independent accumulators (4 float4 loads in flight per thread).
// ---------------------------------------------------------------------------
#define TCH 64
#define NCH (T / TCH)  // 32
__global__ __launch_bounds__(256) void context_partial_kernel(
    const float* __restrict__ enc, float* __restrict__ attn,
    const float2* __restrict__ stats, float* __restrict__ partial) {
  const int b = blockIdx.y;
  const int c = blockIdx.x;
  const int tid = threadIdx.x;
  __shared__ float wa[TCH];
  const float2 st = stats[b];
  if (tid < TCH) {
    const float raw = attn[b * T + c * TCH + tid];
    const float w = __expf(raw - st.x) * st.y;
    attn[b * T + c * TCH + tid] = w;  // final normalized weight
    wa[tid] = w;
  }
  __syncthreads();
  float4 a0 = {0, 0, 0, 0}, a1 = {0, 0, 0, 0}, a2 = {0, 0, 0, 0},
         a3 = {0, 0, 0, 0};
  const float4* base = (const float4*)(enc + ((size_t)b * T + c * TCH) * H);
  for (int t = 0; t < TCH; t += 4) {
    float4 e0 = base[(size_t)(t + 0) * (H / 4) + tid];
    float4 e1 = base[(size_t)(t + 1) * (H / 4) + tid];
    float4 e2 = base[(size_t)(t + 2) * (H / 4) + tid];
    float4 e3 = base[(size_t)(t + 3) * (H / 4) + tid];
    const float w0 = wa[t], w1 = wa[t + 1], w2 = wa[t + 2], w3 = wa[t + 3];
    a0.x = fmaf(w0, e0.x, a0.x); a0.y = fmaf(w0, e0.y, a0.y);
    a0.z = fmaf(w0, e0.z, a0.z); a0.w = fmaf(w0, e0.w, a0.w);
    a1.x = fmaf(w1, e1.x, a1.x); a1.y = fmaf(w1, e1.y, a1.y);
    a1.z = fmaf(w1, e1.z, a1.z); a1.w = fmaf(w1, e1.w, a1.w);
    a2.x = fmaf(w2, e2.x, a2.x); a2.y = fmaf(w2, e2.y, a2.y);
    a2.z = fmaf(w2, e2.z, a2.z); a2.w = fmaf(w2, e2.w, a2.w);
    a3.x = fmaf(w3, e3.x, a3.x); a3.y = fmaf(w3, e3.y, a3.y);
    a3.z = fmaf(w3, e3.z, a3.z); a3.w = fmaf(w3, e3.w, a3.w);
  }
  float4 r;
  r.x = (a0.x + a1.x) + (a2.x + a3.x);
  r.y = (a0.y + a1.y) + (a2.y + a3.y);
  r.z = (a0.z + a1.z) + (a2.z + a3.z);
  r.w = (a0.w + a1.w) + (a2.w + a3.w);
  ((float4*)(partial + ((size_t)b * NCH + c) * H))[tid] = r;
}

// ---------------------------------------------------------------------------
// K5: context[b,:] = sum_c partial[b,c,:]. grid B, 256 threads, unrolled 8.
// ---------------------------------------------------------------------------
__global__ __launch_bounds__(256) void context_reduce_kernel(
    const float* __restrict__ partial, float* __restrict__ ctx) {
  const int b = blockIdx.x;
  const int tid = threadIdx.x;
  float4 acc = {0, 0, 0, 0};
  const float4* p = (const float4*)(partial + (size_t)b * NCH * H);
#pragma unroll 8
  for (int c = 0; c < NCH; ++c) {
    float4 e = p[c * (H / 4) + tid];
    acc.x += e.x; acc.y += e.y; acc.z += e.z; acc.w += e.w;
  }
  ((float4*)(ctx + b * H))[tid] = acc;
}

extern "C" void kernel_launch(void* const* d_in, const int* in_sizes, int n_in,
                              void* d_out, int out_size, void* d_ws,
                              size_t ws_size, hipStream_t stream) {
  const float* hidden = (const float*)d_in[0];  // [B,H]
  const float* enc = (const float*)d_in[1];     // [B,T,H]
  const float* W = (const float*)d_in[2];       // [H,H]

  float* out = (float*)d_out;
  float* out_ctx = out;           // [B,H]
  float* out_attn = out + B * H;  // [B,T]

  float* v = (float*)d_ws;                 // B*H floats
  float* partial = v + B * H;              // B*NCH*H floats
  float2* stats = (float2*)(partial + B * NCH * H);  // B float2

  compute_v_kernel<<<dim3(H / 64, B), 256, 0, stream>>>(hidden, W, v);
  scores_kernel<<<dim3(T / 64, B), 256, 0, stream>>>(enc, v, out_attn);
  softmax_stats_kernel<<<B, 256, 0, stream>>>(out_attn, stats);
  context_partial_kernel<<<dim3(NCH, B), 256, 0, stream>>>(enc, out_attn, stats,
                                                           partial);
  context_reduce_kernel<<<B, 256, 0, stream>>>(partial, out_ctx);
}

// Round 5
// 424.343 us; speedup vs baseline: 1.1083x; 1.0003x over previous
//
#include <hip/hip_runtime.h>

#define B 32
#define T 2048
#define H 1024

// ---------------------------------------------------------------------------
// K1: v[b,h] = sum_o hidden[b,o] * W[o,h]  (v[b] = hidden[b] @ W)
// grid (H/64, B), 256 threads = 4 o-groups x 64 h-lanes, 8 accumulators per
// group, LDS reduce across groups. Also zeroes the (0xAA-poisoned) ctx output
// region so K4 can atomicAdd into it.
// ---------------------------------------------------------------------------
__global__ __launch_bounds__(256) void compute_v_kernel(
    const float* __restrict__ hidden, const float* __restrict__ W,
    float* __restrict__ v, float* __restrict__ ctx) {
  const int b = blockIdx.y;
  const int og = threadIdx.x >> 6;
  const int hl = threadIdx.x & 63;
  const int h = blockIdx.x * 64 + hl;
  __shared__ float sh[H];
  __shared__ float red[4][64];
  if (blockIdx.x == 0) {
    for (int i = threadIdx.x; i < H; i += 256) ctx[b * H + i] = 0.f;
  }
  for (int i = threadIdx.x; i < H; i += 256) sh[i] = hidden[b * H + i];
  __syncthreads();
  float acc[8] = {0.f, 0.f, 0.f, 0.f, 0.f, 0.f, 0.f, 0.f};
  const int ob = og * 256;
  for (int oo = 0; oo < 256; oo += 8) {
#pragma unroll
    for (int k = 0; k < 8; ++k) {
      const int o = ob + oo + k;
      acc[k] = fmaf(sh[o], W[(size_t)o * H + h], acc[k]);
    }
  }
  float a = ((acc[0] + acc[1]) + (acc[2] + acc[3])) +
            ((acc[4] + acc[5]) + (acc[6] + acc[7]));
  red[og][hl] = a;
  __syncthreads();
  if (og == 0)
    v[b * H + h] = (red[0][hl] + red[1][hl]) + (red[2][hl] + red[3][hl]);
}

// ---------------------------------------------------------------------------
// K2: score[b,t] = dot(enc[b,t,:], v[b,:])  (raw scores -> out_attn region)
// grid (T/64, B) = 1024 blocks, 256 threads = 4 waves, 16 rows/wave,
// 4 rows per iteration -> 16 float4 loads in flight per thread; 4 parallel
// shfl-reduce chains; lane 0 stores one float4 of 4 scores.
// ---------------------------------------------------------------------------
__global__ __launch_bounds__(256) void scores_kernel(
    const float* __restrict__ enc, const float* __restrict__ v,
    float* __restrict__ score) {
  const int b = blockIdx.y;
  const int wave = threadIdx.x >> 6;
  const int lane = threadIdx.x & 63;
  const float4* v4 = (const float4*)(v + b * H);
  float4 vr[4];
#pragma unroll
  for (int j = 0; j < 4; ++j) vr[j] = v4[j * 64 + lane];
  const float4* ebase = (const float4*)(enc + (size_t)b * T * H);
  const int t0 = blockIdx.x * 64 + wave * 16;
  for (int it = 0; it < 16; it += 4) {
    const int t = t0 + it;
    float4 e[4][4];
#pragma unroll
    for (int r = 0; r < 4; ++r) {
      const float4* ep = ebase + (size_t)(t + r) * (H / 4);
#pragma unroll
      for (int j = 0; j < 4; ++j) e[r][j] = ep[j * 64 + lane];
    }
    float a[4] = {0.f, 0.f, 0.f, 0.f};
#pragma unroll
    for (int r = 0; r < 4; ++r) {
#pragma unroll
      for (int j = 0; j < 4; ++j) {
        a[r] += e[r][j].x * vr[j].x + e[r][j].y * vr[j].y +
                e[r][j].z * vr[j].z + e[r][j].w * vr[j].w;
      }
    }
#pragma unroll
    for (int off = 32; off; off >>= 1) {
#pragma unroll
      for (int r = 0; r < 4; ++r) a[r] += __shfl_down(a[r], off, 64);
    }
    if (lane == 0)
      *(float4*)(score + b * T + t) = make_float4(a[0], a[1], a[2], a[3]);
  }
}

// ---------------------------------------------------------------------------
// K3: per-b softmax stats: stats[b] = {max, 1/sum(exp(x-max))}.
// ---------------------------------------------------------------------------
__global__ __launch_bounds__(256) void softmax_stats_kernel(
    const float* __restrict__ score, float2* __restrict__ stats) {
  const int b = blockIdx.x;
  const int tid = threadIdx.x;
  const int wave = tid >> 6;
  const int lane = tid & 63;
  __shared__ float red[4];
  const float* row = score + b * T;

  float x[8];
  float m = -1e30f;
#pragma unroll
  for (int j = 0; j < 8; ++j) {
    x[j] = row[j * 256 + tid];
    m = fmaxf(m, x[j]);
  }
#pragma unroll
  for (int off = 32; off; off >>= 1) m = fmaxf(m, __shfl_down(m, off, 64));
  if (lane == 0) red[wave] = m;
  __syncthreads();
  m = fmaxf(fmaxf(red[0], red[1]), fmaxf(red[2], red[3]));
  __syncthreads();

  float s = 0.f;
#pragma unroll
  for (int j = 0; j < 8; ++j) s += __expf(x[j] - m);
#pragma unroll
  for (int off = 32; off; off >>= 1) s += __shfl_down(s, off, 64);
  if (lane == 0) red[wave] = s;
  __syncthreads();
  if (tid == 0) {
    const float total = (red[0] + red[1]) + (red[2] + red[3]);
    stats[b] = make_float2(m, 1.f / total);
  }
}

// ---------------------------------------------------------------------------
// K4: fused normalize + context accumulate over a 64-row t-chunk.
// grid (T/64, B) = 1024 blocks, 256 threads; thread owns one float4 of H.
// REVERSED block mapping: earliest blocks read the enc lines K2 touched last
// (enc = 256 MB = L3 size -> LRU tail reuse). t-loop unrolled 8 deep.
// Accumulates directly into ctx via atomicAdd (32 adds/address, zeroed by K1).
// ---------------------------------------------------------------------------
#define TCH 64
#define NCH (T / TCH)  // 32
__global__ __launch_bounds__(256) void context_kernel(
    const float* __restrict__ enc, float* __restrict__ attn,
    const float2* __restrict__ stats, float* __restrict__ ctx) {
  const int b = (B - 1) - blockIdx.y;
  const int c = (NCH - 1) - blockIdx.x;
  const int tid = threadIdx.x;
  __shared__ float wa[TCH];
  const float2 st = stats[b];
  if (tid < TCH) {
    const float raw = attn[b * T + c * TCH + tid];
    const float w = __expf(raw - st.x) * st.y;
    attn[b * T + c * TCH + tid] = w;  // final normalized weight to output
    wa[tid] = w;
  }
  __syncthreads();
  float4 a0 = {0, 0, 0, 0}, a1 = {0, 0, 0, 0}, a2 = {0, 0, 0, 0},
         a3 = {0, 0, 0, 0};
  const float4* base = (const float4*)(enc + ((size_t)b * T + c * TCH) * H);
  for (int t = 0; t < TCH; t += 8) {
    float4 e0 = base[(size_t)(t + 0) * (H / 4) + tid];
    float4 e1 = base[(size_t)(t + 1) * (H / 4) + tid];
    float4 e2 = base[(size_t)(t + 2) * (H / 4) + tid];
    float4 e3 = base[(size_t)(t + 3) * (H / 4) + tid];
    float4 e4 = base[(size_t)(t + 4) * (H / 4) + tid];
    float4 e5 = base[(size_t)(t + 5) * (H / 4) + tid];
    float4 e6 = base[(size_t)(t + 6) * (H / 4) + tid];
    float4 e7 = base[(size_t)(t + 7) * (H / 4) + tid];
    const float w0 = wa[t + 0], w1 = wa[t + 1], w2 = wa[t + 2],
                w3 = wa[t + 3], w4 = wa[t + 4], w5 = wa[t + 5],
                w6 = wa[t + 6], w7 = wa[t + 7];
    a0.x = fmaf(w0, e0.x, a0.x); a0.y = fmaf(w0, e0.y, a0.y);
    a0.z = fmaf(w0, e0.z, a0.z); a0.w = fmaf(w0, e0.w, a0.w);
    a1.x = fmaf(w1, e1.x, a1.x); a1.y = fmaf(w1, e1.y, a1.y);
    a1.z = fmaf(w1, e1.z, a1.z); a1.w = fmaf(w1, e1.w, a1.w);
    a2.x = fmaf(w2, e2.x, a2.x); a2.y = fmaf(w2, e2.y, a2.y);
    a2.z = fmaf(w2, e2.z, a2.z); a2.w = fmaf(w2, e2.w, a2.w);
    a3.x = fmaf(w3, e3.x, a3.x); a3.y = fmaf(w3, e3.y, a3.y);
    a3.z = fmaf(w3, e3.z, a3.z); a3.w = fmaf(w3, e3.w, a3.w);
    a0.x = fmaf(w4, e4.x, a0.x); a0.y = fmaf(w4, e4.y, a0.y);
    a0.z = fmaf(w4, e4.z, a0.z); a0.w = fmaf(w4, e4.w, a0.w);
    a1.x = fmaf(w5, e5.x, a1.x); a1.y = fmaf(w5, e5.y, a1.y);
    a1.z = fmaf(w5, e5.z, a1.z); a1.w = fmaf(w5, e5.w, a1.w);
    a2.x = fmaf(w6, e6.x, a2.x); a2.y = fmaf(w6, e6.y, a2.y);
    a2.z = fmaf(w6, e6.z, a2.z); a2.w = fmaf(w6, e6.w, a2.w);
    a3.x = fmaf(w7, e7.x, a3.x); a3.y = fmaf(w7, e7.y, a3.y);
    a3.z = fmaf(w7, e7.z, a3.z); a3.w = fmaf(w7, e7.w, a3.w);
  }
  float4 r;
  r.x = (a0.x + a1.x) + (a2.x + a3.x);
  r.y = (a0.y + a1.y) + (a2.y + a3.y);
  r.z = (a0.z + a1.z) + (a2.z + a3.z);
  r.w = (a0.w + a1.w) + (a2.w + a3.w);
  float* dst = ctx + (size_t)b * H + tid * 4;
  atomicAdd(dst + 0, r.x);
  atomicAdd(dst + 1, r.y);
  atomicAdd(dst + 2, r.z);
  atomicAdd(dst + 3, r.w);
}

extern "C" void kernel_launch(void* const* d_in, const int* in_sizes, int n_in,
                              void* d_out, int out_size, void* d_ws,
                              size_t ws_size, hipStream_t stream) {
  const float* hidden = (const float*)d_in[0];  // [B,H]
  const float* enc = (const float*)d_in[1];     // [B,T,H]
  const float* W = (const float*)d_in[2];       // [H,H]

  float* out = (float*)d_out;
  float* out_ctx = out;           // [B,H]
  float* out_attn = out + B * H;  // [B,T]

  float* v = (float*)d_ws;                       // B*H floats
  float2* stats = (float2*)(v + B * H);          // B float2

  compute_v_kernel<<<dim3(H / 64, B), 256, 0, stream>>>(hidden, W, v, out_ctx);
  scores_kernel<<<dim3(T / 64, B), 256, 0, stream>>>(enc, v, out_attn);
  softmax_stats_kernel<<<B, 256, 0, stream>>>(out_attn, stats);
  context_kernel<<<dim3(NCH, B), 256, 0, stream>>>(enc, out_attn, stats,
                                                   out_ctx);
}